// Round 4
// baseline (1083.506 us; speedup 1.0000x reference)
//
#include <hip/hip_runtime.h>

#define N_NODES 100000
#define E_EDGES 1600000
#define L_LAYERS 3
#define G_GRAPHS 128
#define OUT_F 10
#define BN_EPS 1e-5f

#define NB4 (N_NODES / 4)                 // 25000 int4 chunks
#define SCAN_BLOCKS ((NB4 + 255) / 256)   // 98
#define BSHIFT 7                          // 128 nodes per coarse bucket
#define NBUCK ((N_NODES + 127) >> 7)      // 782

// -------------------- CSR build: degree histogram (int4) -----------------
__global__ __launch_bounds__(256) void deg_kernel(const int* __restrict__ dst,
                                                  int* __restrict__ deg) {
    int i = blockIdx.x * blockDim.x + threadIdx.x;   // E/4 threads
    if (i < E_EDGES / 4) {
        int4 d = reinterpret_cast<const int4*>(dst)[i];
        atomicAdd(&deg[d.x], 1);
        atomicAdd(&deg[d.y], 1);
        atomicAdd(&deg[d.z], 1);
        atomicAdd(&deg[d.w], 1);
    }
}

// -------------------- scan phase A: per-block sums -----------------------
__global__ __launch_bounds__(256) void scanA_kernel(const int* __restrict__ deg,
                                                    int* __restrict__ bsum) {
    __shared__ int red[256];
    int t = threadIdx.x;
    int i4 = blockIdx.x * 256 + t;
    int s = 0;
    if (i4 < NB4) {
        int4 v = reinterpret_cast<const int4*>(deg)[i4];
        s = v.x + v.y + v.z + v.w;
    }
    red[t] = s;
    __syncthreads();
    for (int off = 128; off > 0; off >>= 1) {
        if (t < off) red[t] += red[t + off];
        __syncthreads();
    }
    if (t == 0) bsum[blockIdx.x] = red[0];
}

// -------------------- scan phase B: scan the block sums ------------------
__global__ __launch_bounds__(128) void scanB_kernel(int* __restrict__ bsum,
                                                    int* __restrict__ rowptr) {
    __shared__ int p[128];
    int t = threadIdx.x;
    int v = (t < SCAN_BLOCKS) ? bsum[t] : 0;
    p[t] = v;
    __syncthreads();
    for (int off = 1; off < 128; off <<= 1) {
        int u = (t >= off) ? p[t - off] : 0;
        __syncthreads();
        p[t] += u;
        __syncthreads();
    }
    if (t < SCAN_BLOCKS) bsum[t] = p[t] - v;      // exclusive block offset
    if (t == 127) rowptr[N_NODES] = p[127];       // total
}

// ---------- scan phase C: write rowptr + cursor + bucket cursors ---------
__global__ __launch_bounds__(256) void scanC_kernel(
    const int* __restrict__ deg, const int* __restrict__ bsum,
    int* __restrict__ rowptr, int* __restrict__ cursor,
    int* __restrict__ bcursor) {
    __shared__ int ts[256];
    int t = threadIdx.x;
    int i4 = blockIdx.x * 256 + t;
    int4 v = make_int4(0, 0, 0, 0);
    if (i4 < NB4) v = reinterpret_cast<const int4*>(deg)[i4];
    int s = v.x + v.y + v.z + v.w;
    ts[t] = s;
    __syncthreads();
    for (int off = 1; off < 256; off <<= 1) {
        int u = (t >= off) ? ts[t - off] : 0;
        __syncthreads();
        ts[t] += u;
        __syncthreads();
    }
    if (i4 < NB4) {
        int base = bsum[blockIdx.x] + ts[t] - s;   // exclusive prefix
        int4 rp;
        rp.x = base;
        rp.y = rp.x + v.x;
        rp.z = rp.y + v.y;
        rp.w = rp.z + v.z;
        reinterpret_cast<int4*>(rowptr)[i4] = rp;
        reinterpret_cast<int4*>(cursor)[i4] = rp;
        if ((i4 & 31) == 0) bcursor[i4 >> 5] = rp.x;   // node 4*i4 = 128*(i4>>5)
    }
}

// ------------- fill pass A: coarse-bucket the edge pairs -----------------
__global__ __launch_bounds__(256) void fillA_kernel(
    const int* __restrict__ src, const int* __restrict__ dst,
    int* __restrict__ bcursor, int2* __restrict__ epair) {
    int e = blockIdx.x * blockDim.x + threadIdx.x;
    if (e < E_EDGES) {
        int d = dst[e];
        int p = atomicAdd(&bcursor[d >> BSHIFT], 1);
        epair[p] = make_int2(src[e], d);
    }
}

// ------------- fill pass B: fine scatter within hot bucket window --------
// XCD-chunked block swizzle keeps each bucket's position window in one L2.
__global__ __launch_bounds__(256) void fillB_kernel(
    const int2* __restrict__ epair, int* __restrict__ cursor,
    int* __restrict__ nbr) {
    int nwg = gridDim.x;
    int wg = blockIdx.x;
    int q = nwg >> 3, r = nwg & 7;
    int xcd = wg & 7, sub = wg >> 3;
    int swz = (xcd < r ? xcd * (q + 1) : r * (q + 1) + (xcd - r) * q) + sub;
    int e = swz * 256 + threadIdx.x;
    if (e < E_EDGES) {
        int2 p = epair[e];
        int pos = atomicAdd(&cursor[p.y], 1);
        nbr[pos] = p.x;
    }
}

// ------- fused gather + GEMM1 + BN stats: h = (x+sum_nbr x) @ W1 + b1 ----
__global__ __launch_bounds__(256) void gemm1_fused_kernel(
    const float* __restrict__ xin, const int* __restrict__ rowptr,
    const int* __restrict__ nbr, const float* __restrict__ W1,
    const float* __restrict__ b1, float* __restrict__ h,
    float* __restrict__ stats) {
    __shared__ float sA[64][64];
    __shared__ float sW[64][64];
    __shared__ float red[512];
    int tid = threadIdx.x;
    int row0 = blockIdx.x * 64;

    for (int i = tid; i < 1024; i += 256)
        reinterpret_cast<float4*>(&sW[0][0])[i] = reinterpret_cast<const float4*>(W1)[i];

    // gather directly into the LDS A-tile (no AGG round-trip)
    int c = tid & 15;
    int rl = tid >> 4;
    for (int rr = 0; rr < 4; ++rr) {
        int r = rl + 16 * rr;
        int gr = row0 + r;
        float4 acc = make_float4(0.f, 0.f, 0.f, 0.f);
        if (gr < N_NODES) {
            acc = reinterpret_cast<const float4*>(xin)[gr * 16 + c];
            int beg = rowptr[gr], end = rowptr[gr + 1];
            for (int j = beg; j < end; ++j) {
                float4 v = reinterpret_cast<const float4*>(xin)[nbr[j] * 16 + c];
                acc.x += v.x; acc.y += v.y; acc.z += v.z; acc.w += v.w;
            }
        }
        *reinterpret_cast<float4*>(&sA[r][c * 4]) = acc;
    }
    __syncthreads();

    int cc = tid & 63;
    int rbase = (tid >> 6) * 16;
    float bias = b1[cc];
    float lsum = 0.f, lsq = 0.f;
    for (int i = 0; i < 16; ++i) {
        int r = rbase + i;
        int gr = row0 + r;
        float acc = bias;
        #pragma unroll
        for (int k = 0; k < 64; ++k) acc += sA[r][k] * sW[k][cc];
        if (gr < N_NODES) {
            h[(size_t)gr * 64 + cc] = acc;
            lsum += acc;
            lsq += acc * acc;
        }
    }
    red[tid] = lsum;
    red[256 + tid] = lsq;
    __syncthreads();
    if (tid < 64) {
        float s = red[tid] + red[tid + 64] + red[tid + 128] + red[tid + 192];
        float q = red[256 + tid] + red[256 + tid + 64] + red[256 + tid + 128] + red[256 + tid + 192];
        unsafeAtomicAdd(&stats[tid], s);
        unsafeAtomicAdd(&stats[64 + tid], q);
    }
}

// -- GEMM2 + pool (BN finalize folded): xn=relu(h*sc+sh)@W2+b2; pool += ---
__global__ __launch_bounds__(256) void gemm2_pool_kernel(
    float* __restrict__ h, const float* __restrict__ stats,
    const float* __restrict__ gamma, const float* __restrict__ beta,
    const float* __restrict__ W2, const float* __restrict__ b2,
    const int* __restrict__ batch, float* __restrict__ pooled) {
    __shared__ float sA[64][64];
    __shared__ float sW[64][64];
    __shared__ float sSc[64];
    __shared__ float sSh[64];
    __shared__ int sB[64];
    int tid = threadIdx.x;
    int row0 = blockIdx.x * 64;

    if (tid < 64) {
        float mu = stats[tid] * (1.0f / N_NODES);
        float var = stats[64 + tid] * (1.0f / N_NODES) - mu * mu;
        float sc = gamma[tid] * rsqrtf(var + BN_EPS);
        sSc[tid] = sc;
        sSh[tid] = beta[tid] - mu * sc;
        int gr = row0 + tid;
        sB[tid] = (gr < N_NODES) ? batch[gr] : -1;
    }
    for (int i = tid; i < 1024; i += 256)
        reinterpret_cast<float4*>(&sW[0][0])[i] = reinterpret_cast<const float4*>(W2)[i];
    __syncthreads();

    for (int i = tid; i < 1024; i += 256) {
        int r = i >> 4;
        int gr = row0 + r;
        float4 a = make_float4(0.f, 0.f, 0.f, 0.f);
        if (gr < N_NODES) {
            float4 hv = reinterpret_cast<const float4*>(h)[gr * 16 + (i & 15)];
            int c0 = (i & 15) << 2;
            a.x = fmaxf(fmaf(hv.x, sSc[c0 + 0], sSh[c0 + 0]), 0.f);
            a.y = fmaxf(fmaf(hv.y, sSc[c0 + 1], sSh[c0 + 1]), 0.f);
            a.z = fmaxf(fmaf(hv.z, sSc[c0 + 2], sSh[c0 + 2]), 0.f);
            a.w = fmaxf(fmaf(hv.w, sSc[c0 + 3], sSh[c0 + 3]), 0.f);
        }
        reinterpret_cast<float4*>(&sA[0][0])[i] = a;
    }
    __syncthreads();

    int c = tid & 63;
    int rbase = (tid >> 6) * 16;
    float bias = b2[c];
    float pacc = 0.f;
    int curb = -1;
    for (int i = 0; i < 16; ++i) {
        int r = rbase + i;
        int gr = row0 + r;
        float acc = bias;
        #pragma unroll
        for (int k = 0; k < 64; ++k) acc += sA[r][k] * sW[k][c];
        if (gr < N_NODES) {
            h[(size_t)gr * 64 + c] = acc;
            int b = sB[r];
            if (b != curb) {
                if (curb >= 0) unsafeAtomicAdd(&pooled[curb * 64 + c], pacc);
                curb = b;
                pacc = 0.f;
            }
            pacc += acc;
        }
    }
    if (curb >= 0) unsafeAtomicAdd(&pooled[curb * 64 + c], pacc);
}

// -------------------- output: score += pooled @ Wout + bout --------------
__global__ void out_kernel(const float* __restrict__ pooled,
                           const float* __restrict__ Wout,
                           const float* __restrict__ bout,
                           float* __restrict__ score) {
    int idx = blockIdx.x * blockDim.x + threadIdx.x;
    if (idx >= G_GRAPHS * OUT_F) return;
    int g = idx / OUT_F;
    int o = idx - g * OUT_F;
    float acc = bout[o];
    #pragma unroll
    for (int k = 0; k < 64; ++k) acc += pooled[g * 64 + k] * Wout[k * OUT_F + o];
    score[idx] += acc;
}

extern "C" void kernel_launch(void* const* d_in, const int* in_sizes, int n_in,
                              void* d_out, int out_size, void* d_ws, size_t ws_size,
                              hipStream_t stream) {
    const float* x     = (const float*)d_in[0];
    const int*   ei    = (const int*)d_in[1];
    const int*   batch = (const int*)d_in[2];
    const float* W1    = (const float*)d_in[3];
    const float* b1    = (const float*)d_in[4];
    const float* gamma = (const float*)d_in[5];
    const float* beta  = (const float*)d_in[6];
    const float* W2    = (const float*)d_in[7];
    const float* b2    = (const float*)d_in[8];
    const float* Wout  = (const float*)d_in[9];
    const float* bout  = (const float*)d_in[10];
    float* out = (float*)d_out;

    float* B0     = (float*)d_ws;                            // N*64
    float* B1     = B0 + (size_t)N_NODES * 64;               // N*64
    float* stats  = B1 + (size_t)N_NODES * 64;               // 128
    float* pooled = stats + 128;                             // G*64 (adjacent)
    int*   deg    = (int*)(pooled + (size_t)G_GRAPHS * 64);  // N
    int*   rowptr = deg + N_NODES;                           // N+4
    int*   cursor = rowptr + N_NODES + 4;                    // N
    int*   bcursor= cursor + N_NODES;                        // NBUCK (padded 784)
    int*   bsum   = bcursor + 784;                           // SCAN_BLOCKS (padded 128)
    int*   nbr    = bsum + 128;                              // E
    int2*  epair  = (int2*)(nbr + E_EDGES);                  // E pairs

    const int* src = ei;
    const int* dst = ei + E_EDGES;

    hipMemsetAsync(d_out, 0, (size_t)G_GRAPHS * OUT_F * sizeof(float), stream);
    hipMemsetAsync(deg, 0, (size_t)N_NODES * sizeof(int), stream);

    deg_kernel<<<(E_EDGES / 4 + 255) / 256, 256, 0, stream>>>(dst, deg);
    scanA_kernel<<<SCAN_BLOCKS, 256, 0, stream>>>(deg, bsum);
    scanB_kernel<<<1, 128, 0, stream>>>(bsum, rowptr);
    scanC_kernel<<<SCAN_BLOCKS, 256, 0, stream>>>(deg, bsum, rowptr, cursor, bcursor);
    int eb = (E_EDGES + 255) / 256;
    fillA_kernel<<<eb, 256, 0, stream>>>(src, dst, bcursor, epair);
    fillB_kernel<<<eb, 256, 0, stream>>>(epair, cursor, nbr);

    int nb = (N_NODES + 63) / 64;

    for (int l = 0; l < L_LAYERS; ++l) {
        const float* xin;
        float* hbuf;
        if (l == 0)      { xin = x;  hbuf = B0; }
        else if (l == 1) { xin = B0; hbuf = B1; }
        else             { xin = B1; hbuf = B0; }

        // stats (128) + pooled (G*64) are adjacent: one memset
        hipMemsetAsync(stats, 0, (128 + (size_t)G_GRAPHS * 64) * sizeof(float), stream);

        gemm1_fused_kernel<<<nb, 256, 0, stream>>>(xin, rowptr, nbr,
            W1 + l * 64 * 64, b1 + l * 64, hbuf, stats);
        gemm2_pool_kernel<<<nb, 256, 0, stream>>>(hbuf, stats,
            gamma + l * 64, beta + l * 64, W2 + l * 64 * 64, b2 + l * 64, batch, pooled);
        out_kernel<<<(G_GRAPHS * OUT_F + 127) / 128, 128, 0, stream>>>(
            pooled, Wout + l * 64 * OUT_F, bout + l * OUT_F, out);
    }
}

// Round 5
// 726.870 us; speedup vs baseline: 1.4906x; 1.4906x over previous
//
#include <hip/hip_runtime.h>

#define N_NODES 100000
#define E_EDGES 1600000
#define L_LAYERS 3
#define G_GRAPHS 128
#define OUT_F 10
#define BN_EPS 1e-5f

#define NB4 (N_NODES / 4)                 // 25000 int4 chunks
#define SCAN_BLOCKS ((NB4 + 255) / 256)   // 98
#define BSHIFT 7                          // 128-node stripes for XCD ownership
#define CHUNK 2048
#define NCHUNK ((E_EDGES + CHUNK - 1) / CHUNK)   // 782

// -------------------- CSR build: degree histogram (int4) -----------------
__global__ __launch_bounds__(256) void deg_kernel(const int* __restrict__ dst,
                                                  int* __restrict__ deg) {
    int i = blockIdx.x * blockDim.x + threadIdx.x;   // E/4 threads
    if (i < E_EDGES / 4) {
        int4 d = reinterpret_cast<const int4*>(dst)[i];
        atomicAdd(&deg[d.x], 1);
        atomicAdd(&deg[d.y], 1);
        atomicAdd(&deg[d.z], 1);
        atomicAdd(&deg[d.w], 1);
    }
}

// -------------------- scan phase A: per-block sums -----------------------
__global__ __launch_bounds__(256) void scanA_kernel(const int* __restrict__ deg,
                                                    int* __restrict__ bsum) {
    __shared__ int red[256];
    int t = threadIdx.x;
    int i4 = blockIdx.x * 256 + t;
    int s = 0;
    if (i4 < NB4) {
        int4 v = reinterpret_cast<const int4*>(deg)[i4];
        s = v.x + v.y + v.z + v.w;
    }
    red[t] = s;
    __syncthreads();
    for (int off = 128; off > 0; off >>= 1) {
        if (t < off) red[t] += red[t + off];
        __syncthreads();
    }
    if (t == 0) bsum[blockIdx.x] = red[0];
}

// -------------------- scan phase B: scan the block sums ------------------
__global__ __launch_bounds__(128) void scanB_kernel(int* __restrict__ bsum,
                                                    int* __restrict__ rowptr) {
    __shared__ int p[128];
    int t = threadIdx.x;
    int v = (t < SCAN_BLOCKS) ? bsum[t] : 0;
    p[t] = v;
    __syncthreads();
    for (int off = 1; off < 128; off <<= 1) {
        int u = (t >= off) ? p[t - off] : 0;
        __syncthreads();
        p[t] += u;
        __syncthreads();
    }
    if (t < SCAN_BLOCKS) bsum[t] = p[t] - v;      // exclusive block offset
    if (t == 127) rowptr[N_NODES] = p[127];       // total
}

// ---------- scan phase C: write rowptr + cursor --------------------------
__global__ __launch_bounds__(256) void scanC_kernel(
    const int* __restrict__ deg, const int* __restrict__ bsum,
    int* __restrict__ rowptr, int* __restrict__ cursor) {
    __shared__ int ts[256];
    int t = threadIdx.x;
    int i4 = blockIdx.x * 256 + t;
    int4 v = make_int4(0, 0, 0, 0);
    if (i4 < NB4) v = reinterpret_cast<const int4*>(deg)[i4];
    int s = v.x + v.y + v.z + v.w;
    ts[t] = s;
    __syncthreads();
    for (int off = 1; off < 256; off <<= 1) {
        int u = (t >= off) ? ts[t - off] : 0;
        __syncthreads();
        ts[t] += u;
        __syncthreads();
    }
    if (i4 < NB4) {
        int base = bsum[blockIdx.x] + ts[t] - s;   // exclusive prefix
        int4 rp;
        rp.x = base;
        rp.y = rp.x + v.x;
        rp.z = rp.y + v.y;
        rp.w = rp.z + v.z;
        reinterpret_cast<int4*>(rowptr)[i4] = rp;
        reinterpret_cast<int4*>(cursor)[i4] = rp;
    }
}

// ------------- CSR fill: XCD-striped scatter ------------------------------
// Node-stripe (128 nodes) s is owned by XCD s&7. Block b (on XCD b&7 by the
// round-robin dispatch heuristic) scans a 2048-edge chunk and scatters only
// edges whose dst-stripe it owns -> all writes to a given nbr region come
// from ONE XCD's L2, so 64B lines fill completely before writeback.
__global__ __launch_bounds__(256) void fill_kernel(
    const int* __restrict__ src, const int* __restrict__ dst,
    int* __restrict__ cursor, int* __restrict__ nbr) {
    int xcd = blockIdx.x & 7;
    int base = (blockIdx.x >> 3) * CHUNK;
    #pragma unroll
    for (int it = 0; it < CHUNK / 256; ++it) {
        int e = base + it * 256 + threadIdx.x;
        if (e < E_EDGES) {
            int d = dst[e];
            if (((d >> BSHIFT) & 7) == xcd) {
                int pos = atomicAdd(&cursor[d], 1);
                nbr[pos] = src[e];
            }
        }
    }
}

// ------- fused gather + GEMM1 + BN stats: h = (x+sum_nbr x) @ W1 + b1 ----
__global__ __launch_bounds__(256) void gemm1_fused_kernel(
    const float* __restrict__ xin, const int* __restrict__ rowptr,
    const int* __restrict__ nbr, const float* __restrict__ W1,
    const float* __restrict__ b1, float* __restrict__ h,
    float* __restrict__ stats) {
    __shared__ float sA[64][64];
    __shared__ float sW[64][64];
    __shared__ float red[512];
    int tid = threadIdx.x;
    int row0 = blockIdx.x * 64;

    for (int i = tid; i < 1024; i += 256)
        reinterpret_cast<float4*>(&sW[0][0])[i] = reinterpret_cast<const float4*>(W1)[i];

    // gather directly into the LDS A-tile (no AGG round-trip)
    int c = tid & 15;
    int rl = tid >> 4;
    for (int rr = 0; rr < 4; ++rr) {
        int r = rl + 16 * rr;
        int gr = row0 + r;
        float4 acc = make_float4(0.f, 0.f, 0.f, 0.f);
        if (gr < N_NODES) {
            acc = reinterpret_cast<const float4*>(xin)[gr * 16 + c];
            int beg = rowptr[gr], end = rowptr[gr + 1];
            for (int j = beg; j < end; ++j) {
                float4 v = reinterpret_cast<const float4*>(xin)[nbr[j] * 16 + c];
                acc.x += v.x; acc.y += v.y; acc.z += v.z; acc.w += v.w;
            }
        }
        *reinterpret_cast<float4*>(&sA[r][c * 4]) = acc;
    }
    __syncthreads();

    int cc = tid & 63;
    int rbase = (tid >> 6) * 16;
    float bias = b1[cc];
    float lsum = 0.f, lsq = 0.f;
    for (int i = 0; i < 16; ++i) {
        int r = rbase + i;
        int gr = row0 + r;
        float acc = bias;
        #pragma unroll
        for (int k = 0; k < 64; ++k) acc += sA[r][k] * sW[k][cc];
        if (gr < N_NODES) {
            h[(size_t)gr * 64 + cc] = acc;
            lsum += acc;
            lsq += acc * acc;
        }
    }
    red[tid] = lsum;
    red[256 + tid] = lsq;
    __syncthreads();
    if (tid < 64) {
        float s = red[tid] + red[tid + 64] + red[tid + 128] + red[tid + 192];
        float q = red[256 + tid] + red[256 + tid + 64] + red[256 + tid + 128] + red[256 + tid + 192];
        unsafeAtomicAdd(&stats[tid], s);
        unsafeAtomicAdd(&stats[64 + tid], q);
    }
}

// -- GEMM2 + pool (BN finalize folded): xn=relu(h*sc+sh)@W2+b2; pool += ---
__global__ __launch_bounds__(256) void gemm2_pool_kernel(
    float* __restrict__ h, const float* __restrict__ stats,
    const float* __restrict__ gamma, const float* __restrict__ beta,
    const float* __restrict__ W2, const float* __restrict__ b2,
    const int* __restrict__ batch, float* __restrict__ pooled) {
    __shared__ float sA[64][64];
    __shared__ float sW[64][64];
    __shared__ float sSc[64];
    __shared__ float sSh[64];
    __shared__ int sB[64];
    int tid = threadIdx.x;
    int row0 = blockIdx.x * 64;

    if (tid < 64) {
        float mu = stats[tid] * (1.0f / N_NODES);
        float var = stats[64 + tid] * (1.0f / N_NODES) - mu * mu;
        float sc = gamma[tid] * rsqrtf(var + BN_EPS);
        sSc[tid] = sc;
        sSh[tid] = beta[tid] - mu * sc;
        int gr = row0 + tid;
        sB[tid] = (gr < N_NODES) ? batch[gr] : -1;
    }
    for (int i = tid; i < 1024; i += 256)
        reinterpret_cast<float4*>(&sW[0][0])[i] = reinterpret_cast<const float4*>(W2)[i];
    __syncthreads();

    for (int i = tid; i < 1024; i += 256) {
        int r = i >> 4;
        int gr = row0 + r;
        float4 a = make_float4(0.f, 0.f, 0.f, 0.f);
        if (gr < N_NODES) {
            float4 hv = reinterpret_cast<const float4*>(h)[gr * 16 + (i & 15)];
            int c0 = (i & 15) << 2;
            a.x = fmaxf(fmaf(hv.x, sSc[c0 + 0], sSh[c0 + 0]), 0.f);
            a.y = fmaxf(fmaf(hv.y, sSc[c0 + 1], sSh[c0 + 1]), 0.f);
            a.z = fmaxf(fmaf(hv.z, sSc[c0 + 2], sSh[c0 + 2]), 0.f);
            a.w = fmaxf(fmaf(hv.w, sSc[c0 + 3], sSh[c0 + 3]), 0.f);
        }
        reinterpret_cast<float4*>(&sA[0][0])[i] = a;
    }
    __syncthreads();

    int c = tid & 63;
    int rbase = (tid >> 6) * 16;
    float bias = b2[c];
    float pacc = 0.f;
    int curb = -1;
    for (int i = 0; i < 16; ++i) {
        int r = rbase + i;
        int gr = row0 + r;
        float acc = bias;
        #pragma unroll
        for (int k = 0; k < 64; ++k) acc += sA[r][k] * sW[k][c];
        if (gr < N_NODES) {
            h[(size_t)gr * 64 + c] = acc;
            int b = sB[r];
            if (b != curb) {
                if (curb >= 0) unsafeAtomicAdd(&pooled[curb * 64 + c], pacc);
                curb = b;
                pacc = 0.f;
            }
            pacc += acc;
        }
    }
    if (curb >= 0) unsafeAtomicAdd(&pooled[curb * 64 + c], pacc);
}

// -------------------- output: score += pooled @ Wout + bout --------------
__global__ void out_kernel(const float* __restrict__ pooled,
                           const float* __restrict__ Wout,
                           const float* __restrict__ bout,
                           float* __restrict__ score) {
    int idx = blockIdx.x * blockDim.x + threadIdx.x;
    if (idx >= G_GRAPHS * OUT_F) return;
    int g = idx / OUT_F;
    int o = idx - g * OUT_F;
    float acc = bout[o];
    #pragma unroll
    for (int k = 0; k < 64; ++k) acc += pooled[g * 64 + k] * Wout[k * OUT_F + o];
    score[idx] += acc;
}

extern "C" void kernel_launch(void* const* d_in, const int* in_sizes, int n_in,
                              void* d_out, int out_size, void* d_ws, size_t ws_size,
                              hipStream_t stream) {
    const float* x     = (const float*)d_in[0];
    const int*   ei    = (const int*)d_in[1];
    const int*   batch = (const int*)d_in[2];
    const float* W1    = (const float*)d_in[3];
    const float* b1    = (const float*)d_in[4];
    const float* gamma = (const float*)d_in[5];
    const float* beta  = (const float*)d_in[6];
    const float* W2    = (const float*)d_in[7];
    const float* b2    = (const float*)d_in[8];
    const float* Wout  = (const float*)d_in[9];
    const float* bout  = (const float*)d_in[10];
    float* out = (float*)d_out;

    float* B0     = (float*)d_ws;                            // N*64
    float* B1     = B0 + (size_t)N_NODES * 64;               // N*64
    float* stats  = B1 + (size_t)N_NODES * 64;               // 128
    float* pooled = stats + 128;                             // G*64 (adjacent)
    int*   deg    = (int*)(pooled + (size_t)G_GRAPHS * 64);  // N
    int*   rowptr = deg + N_NODES;                           // N+4
    int*   cursor = rowptr + N_NODES + 4;                    // N
    int*   bsum   = cursor + N_NODES;                        // SCAN_BLOCKS (pad 128)
    int*   nbr    = bsum + 128;                              // E

    const int* src = ei;
    const int* dst = ei + E_EDGES;

    hipMemsetAsync(d_out, 0, (size_t)G_GRAPHS * OUT_F * sizeof(float), stream);
    hipMemsetAsync(deg, 0, (size_t)N_NODES * sizeof(int), stream);

    deg_kernel<<<(E_EDGES / 4 + 255) / 256, 256, 0, stream>>>(dst, deg);
    scanA_kernel<<<SCAN_BLOCKS, 256, 0, stream>>>(deg, bsum);
    scanB_kernel<<<1, 128, 0, stream>>>(bsum, rowptr);
    scanC_kernel<<<SCAN_BLOCKS, 256, 0, stream>>>(deg, bsum, rowptr, cursor);
    fill_kernel<<<NCHUNK * 8, 256, 0, stream>>>(src, dst, cursor, nbr);

    int nb = (N_NODES + 63) / 64;

    for (int l = 0; l < L_LAYERS; ++l) {
        const float* xin;
        float* hbuf;
        if (l == 0)      { xin = x;  hbuf = B0; }
        else if (l == 1) { xin = B0; hbuf = B1; }
        else             { xin = B1; hbuf = B0; }

        // stats (128) + pooled (G*64) are adjacent: one memset
        hipMemsetAsync(stats, 0, (128 + (size_t)G_GRAPHS * 64) * sizeof(float), stream);

        gemm1_fused_kernel<<<nb, 256, 0, stream>>>(xin, rowptr, nbr,
            W1 + l * 64 * 64, b1 + l * 64, hbuf, stats);
        gemm2_pool_kernel<<<nb, 256, 0, stream>>>(hbuf, stats,
            gamma + l * 64, beta + l * 64, W2 + l * 64 * 64, b2 + l * 64, batch, pooled);
        out_kernel<<<(G_GRAPHS * OUT_F + 127) / 128, 128, 0, stream>>>(
            pooled, Wout + l * 64 * OUT_F, bout + l * OUT_F, out);
    }
}

// Round 6
// 627.103 us; speedup vs baseline: 1.7278x; 1.1591x over previous
//
#include <hip/hip_runtime.h>

#define N_NODES 100000
#define E_EDGES 1600000
#define L_LAYERS 3
#define G_GRAPHS 128
#define OUT_F 10
#define BN_EPS 1e-5f

#define NB4 (N_NODES / 4)                 // 25000 int4 chunks
#define SCAN_BLOCKS ((NB4 + 255) / 256)   // 98
#define BSHIFT 7                          // 128-node stripes for XCD ownership
#define CHUNK 2048
#define NCHUNK ((E_EDGES + CHUNK - 1) / CHUNK)   // 782

// -------------------- CSR build: degree histogram (int4) -----------------
__global__ __launch_bounds__(256) void deg_kernel(const int* __restrict__ dst,
                                                  int* __restrict__ deg) {
    int i = blockIdx.x * blockDim.x + threadIdx.x;   // E/4 threads
    if (i < E_EDGES / 4) {
        int4 d = reinterpret_cast<const int4*>(dst)[i];
        atomicAdd(&deg[d.x], 1);
        atomicAdd(&deg[d.y], 1);
        atomicAdd(&deg[d.z], 1);
        atomicAdd(&deg[d.w], 1);
    }
}

// -------------------- scan phase A: per-block sums -----------------------
__global__ __launch_bounds__(256) void scanA_kernel(const int* __restrict__ deg,
                                                    int* __restrict__ bsum) {
    __shared__ int red[256];
    int t = threadIdx.x;
    int i4 = blockIdx.x * 256 + t;
    int s = 0;
    if (i4 < NB4) {
        int4 v = reinterpret_cast<const int4*>(deg)[i4];
        s = v.x + v.y + v.z + v.w;
    }
    red[t] = s;
    __syncthreads();
    for (int off = 128; off > 0; off >>= 1) {
        if (t < off) red[t] += red[t + off];
        __syncthreads();
    }
    if (t == 0) bsum[blockIdx.x] = red[0];
}

// -------------------- scan phase B: scan the block sums ------------------
__global__ __launch_bounds__(128) void scanB_kernel(int* __restrict__ bsum,
                                                    int* __restrict__ rowptr) {
    __shared__ int p[128];
    int t = threadIdx.x;
    int v = (t < SCAN_BLOCKS) ? bsum[t] : 0;
    p[t] = v;
    __syncthreads();
    for (int off = 1; off < 128; off <<= 1) {
        int u = (t >= off) ? p[t - off] : 0;
        __syncthreads();
        p[t] += u;
        __syncthreads();
    }
    if (t < SCAN_BLOCKS) bsum[t] = p[t] - v;      // exclusive block offset
    if (t == 127) rowptr[N_NODES] = p[127];       // total
}

// ---------- scan phase C: write rowptr + cursor --------------------------
__global__ __launch_bounds__(256) void scanC_kernel(
    const int* __restrict__ deg, const int* __restrict__ bsum,
    int* __restrict__ rowptr, int* __restrict__ cursor) {
    __shared__ int ts[256];
    int t = threadIdx.x;
    int i4 = blockIdx.x * 256 + t;
    int4 v = make_int4(0, 0, 0, 0);
    if (i4 < NB4) v = reinterpret_cast<const int4*>(deg)[i4];
    int s = v.x + v.y + v.z + v.w;
    ts[t] = s;
    __syncthreads();
    for (int off = 1; off < 256; off <<= 1) {
        int u = (t >= off) ? ts[t - off] : 0;
        __syncthreads();
        ts[t] += u;
        __syncthreads();
    }
    if (i4 < NB4) {
        int base = bsum[blockIdx.x] + ts[t] - s;   // exclusive prefix
        int4 rp;
        rp.x = base;
        rp.y = rp.x + v.x;
        rp.z = rp.y + v.y;
        rp.w = rp.z + v.z;
        reinterpret_cast<int4*>(rowptr)[i4] = rp;
        reinterpret_cast<int4*>(cursor)[i4] = rp;
    }
}

// ------------- CSR fill: XCD-striped scatter ------------------------------
__global__ __launch_bounds__(256) void fill_kernel(
    const int* __restrict__ src, const int* __restrict__ dst,
    int* __restrict__ cursor, int* __restrict__ nbr) {
    int xcd = blockIdx.x & 7;
    int base = (blockIdx.x >> 3) * CHUNK;
    #pragma unroll
    for (int it = 0; it < CHUNK / 256; ++it) {
        int e = base + it * 256 + threadIdx.x;
        if (e < E_EDGES) {
            int d = dst[e];
            if (((d >> BSHIFT) & 7) == xcd) {
                int pos = atomicAdd(&cursor[d], 1);
                nbr[pos] = src[e];
            }
        }
    }
}

// ------- fused gather + GEMM1 + BN stats: h = (x+sum_nbr x) @ W1 + b1 ----
// LDS = exactly 32KB -> 5 blocks/CU. Gather unrolled x4 for MLP.
__global__ __launch_bounds__(256) void gemm1_fused_kernel(
    const float* __restrict__ xin, const int* __restrict__ rowptr,
    const int* __restrict__ nbr, const float* __restrict__ W1,
    const float* __restrict__ b1, float* __restrict__ h,
    float* __restrict__ stats) {
    __shared__ float sA[64][64];
    __shared__ float sW[64][64];
    int tid = threadIdx.x;
    int row0 = blockIdx.x * 64;

    for (int i = tid; i < 1024; i += 256)
        reinterpret_cast<float4*>(&sW[0][0])[i] = reinterpret_cast<const float4*>(W1)[i];

    // gather directly into the LDS A-tile, 4 neighbors in flight per lane
    int c = tid & 15;
    int rl = tid >> 4;
    for (int rr = 0; rr < 4; ++rr) {
        int r = rl + 16 * rr;
        int gr = row0 + r;
        float4 acc = make_float4(0.f, 0.f, 0.f, 0.f);
        if (gr < N_NODES) {
            acc = reinterpret_cast<const float4*>(xin)[gr * 16 + c];
            int beg = rowptr[gr], end = rowptr[gr + 1];
            int j = beg;
            for (; j + 4 <= end; j += 4) {
                int s0 = nbr[j + 0];
                int s1 = nbr[j + 1];
                int s2 = nbr[j + 2];
                int s3 = nbr[j + 3];
                float4 v0 = reinterpret_cast<const float4*>(xin)[s0 * 16 + c];
                float4 v1 = reinterpret_cast<const float4*>(xin)[s1 * 16 + c];
                float4 v2 = reinterpret_cast<const float4*>(xin)[s2 * 16 + c];
                float4 v3 = reinterpret_cast<const float4*>(xin)[s3 * 16 + c];
                float4 p0 = make_float4(v0.x + v1.x, v0.y + v1.y, v0.z + v1.z, v0.w + v1.w);
                float4 p1 = make_float4(v2.x + v3.x, v2.y + v3.y, v2.z + v3.z, v2.w + v3.w);
                acc.x += p0.x + p1.x;
                acc.y += p0.y + p1.y;
                acc.z += p0.z + p1.z;
                acc.w += p0.w + p1.w;
            }
            for (; j < end; ++j) {
                float4 v = reinterpret_cast<const float4*>(xin)[nbr[j] * 16 + c];
                acc.x += v.x; acc.y += v.y; acc.z += v.z; acc.w += v.w;
            }
        }
        *reinterpret_cast<float4*>(&sA[r][c * 4]) = acc;
    }
    __syncthreads();

    int cc = tid & 63;
    int rbase = (tid >> 6) * 16;
    float bias = b1[cc];
    float lsum = 0.f, lsq = 0.f;
    float hout[16];
    for (int i = 0; i < 16; ++i) {
        int r = rbase + i;
        float acc = bias;
        #pragma unroll
        for (int k = 0; k < 64; ++k) acc += sA[r][k] * sW[k][cc];
        hout[i] = acc;
    }
    for (int i = 0; i < 16; ++i) {
        int gr = row0 + rbase + i;
        if (gr < N_NODES) {
            h[(size_t)gr * 64 + cc] = hout[i];
            lsum += hout[i];
            lsq += hout[i] * hout[i];
        }
    }
    // reuse sA as reduction scratch (all reads of sA are done)
    __syncthreads();
    float* red = &sA[0][0];
    red[tid] = lsum;
    red[256 + tid] = lsq;
    __syncthreads();
    if (tid < 64) {
        float s = red[tid] + red[tid + 64] + red[tid + 128] + red[tid + 192];
        float q = red[256 + tid] + red[256 + tid + 64] + red[256 + tid + 128] + red[256 + tid + 192];
        unsafeAtomicAdd(&stats[tid], s);
        unsafeAtomicAdd(&stats[64 + tid], q);
    }
}

// -- GEMM2 + pool (BN finalize folded): xn=relu(h*sc+sh)@W2+b2; pool += ---
// BN scale/shift per staging thread in registers (i&15 == tid&15 invariant);
// batch read directly from global (L1 broadcast). LDS = exactly 32KB.
__global__ __launch_bounds__(256) void gemm2_pool_kernel(
    float* __restrict__ h, const float* __restrict__ stats,
    const float* __restrict__ gamma, const float* __restrict__ beta,
    const float* __restrict__ W2, const float* __restrict__ b2,
    const int* __restrict__ batch, float* __restrict__ pooled) {
    __shared__ float sA[64][64];
    __shared__ float sW[64][64];
    int tid = threadIdx.x;
    int row0 = blockIdx.x * 64;

    for (int i = tid; i < 1024; i += 256)
        reinterpret_cast<float4*>(&sW[0][0])[i] = reinterpret_cast<const float4*>(W2)[i];

    // per-thread BN scale/shift for its fixed 4 columns c0..c0+3
    int c4 = tid & 15;
    float4 s1 = reinterpret_cast<const float4*>(stats)[c4];
    float4 s2 = reinterpret_cast<const float4*>(stats + 64)[c4];
    float4 g4 = reinterpret_cast<const float4*>(gamma)[c4];
    float4 bt4 = reinterpret_cast<const float4*>(beta)[c4];
    float4 sc, sh;
    {
        float mu, var;
        mu = s1.x * (1.0f / N_NODES); var = s2.x * (1.0f / N_NODES) - mu * mu;
        sc.x = g4.x * rsqrtf(var + BN_EPS); sh.x = bt4.x - mu * sc.x;
        mu = s1.y * (1.0f / N_NODES); var = s2.y * (1.0f / N_NODES) - mu * mu;
        sc.y = g4.y * rsqrtf(var + BN_EPS); sh.y = bt4.y - mu * sc.y;
        mu = s1.z * (1.0f / N_NODES); var = s2.z * (1.0f / N_NODES) - mu * mu;
        sc.z = g4.z * rsqrtf(var + BN_EPS); sh.z = bt4.z - mu * sc.z;
        mu = s1.w * (1.0f / N_NODES); var = s2.w * (1.0f / N_NODES) - mu * mu;
        sc.w = g4.w * rsqrtf(var + BN_EPS); sh.w = bt4.w - mu * sc.w;
    }

    for (int i = tid; i < 1024; i += 256) {
        int r = i >> 4;
        int gr = row0 + r;
        float4 a = make_float4(0.f, 0.f, 0.f, 0.f);
        if (gr < N_NODES) {
            float4 hv = reinterpret_cast<const float4*>(h)[gr * 16 + c4];
            a.x = fmaxf(fmaf(hv.x, sc.x, sh.x), 0.f);
            a.y = fmaxf(fmaf(hv.y, sc.y, sh.y), 0.f);
            a.z = fmaxf(fmaf(hv.z, sc.z, sh.z), 0.f);
            a.w = fmaxf(fmaf(hv.w, sc.w, sh.w), 0.f);
        }
        reinterpret_cast<float4*>(&sA[0][0])[i] = a;
    }
    __syncthreads();

    int c = tid & 63;
    int rbase = (tid >> 6) * 16;
    float bias = b2[c];
    float pacc = 0.f;
    int curb = -1;
    for (int i = 0; i < 16; ++i) {
        int r = rbase + i;
        int gr = row0 + r;
        float acc = bias;
        #pragma unroll
        for (int k = 0; k < 64; ++k) acc += sA[r][k] * sW[k][c];
        if (gr < N_NODES) {
            h[(size_t)gr * 64 + c] = acc;
            int b = batch[gr];
            if (b != curb) {
                if (curb >= 0) unsafeAtomicAdd(&pooled[curb * 64 + c], pacc);
                curb = b;
                pacc = 0.f;
            }
            pacc += acc;
        }
    }
    if (curb >= 0) unsafeAtomicAdd(&pooled[curb * 64 + c], pacc);
}

// -------------------- output: score += pooled @ Wout + bout --------------
__global__ void out_kernel(const float* __restrict__ pooled,
                           const float* __restrict__ Wout,
                           const float* __restrict__ bout,
                           float* __restrict__ score) {
    int idx = blockIdx.x * blockDim.x + threadIdx.x;
    if (idx >= G_GRAPHS * OUT_F) return;
    int g = idx / OUT_F;
    int o = idx - g * OUT_F;
    float acc = bout[o];
    #pragma unroll
    for (int k = 0; k < 64; ++k) acc += pooled[g * 64 + k] * Wout[k * OUT_F + o];
    score[idx] += acc;
}

extern "C" void kernel_launch(void* const* d_in, const int* in_sizes, int n_in,
                              void* d_out, int out_size, void* d_ws, size_t ws_size,
                              hipStream_t stream) {
    const float* x     = (const float*)d_in[0];
    const int*   ei    = (const int*)d_in[1];
    const int*   batch = (const int*)d_in[2];
    const float* W1    = (const float*)d_in[3];
    const float* b1    = (const float*)d_in[4];
    const float* gamma = (const float*)d_in[5];
    const float* beta  = (const float*)d_in[6];
    const float* W2    = (const float*)d_in[7];
    const float* b2    = (const float*)d_in[8];
    const float* Wout  = (const float*)d_in[9];
    const float* bout  = (const float*)d_in[10];
    float* out = (float*)d_out;

    float* B0     = (float*)d_ws;                            // N*64
    float* B1     = B0 + (size_t)N_NODES * 64;               // N*64
    float* stats  = B1 + (size_t)N_NODES * 64;               // 128
    float* pooled = stats + 128;                             // G*64 (adjacent)
    int*   deg    = (int*)(pooled + (size_t)G_GRAPHS * 64);  // N
    int*   rowptr = deg + N_NODES;                           // N+4
    int*   cursor = rowptr + N_NODES + 4;                    // N
    int*   bsum   = cursor + N_NODES;                        // SCAN_BLOCKS (pad 128)
    int*   nbr    = bsum + 128;                              // E

    const int* src = ei;
    const int* dst = ei + E_EDGES;

    hipMemsetAsync(d_out, 0, (size_t)G_GRAPHS * OUT_F * sizeof(float), stream);
    hipMemsetAsync(deg, 0, (size_t)N_NODES * sizeof(int), stream);

    deg_kernel<<<(E_EDGES / 4 + 255) / 256, 256, 0, stream>>>(dst, deg);
    scanA_kernel<<<SCAN_BLOCKS, 256, 0, stream>>>(deg, bsum);
    scanB_kernel<<<1, 128, 0, stream>>>(bsum, rowptr);
    scanC_kernel<<<SCAN_BLOCKS, 256, 0, stream>>>(deg, bsum, rowptr, cursor);
    fill_kernel<<<NCHUNK * 8, 256, 0, stream>>>(src, dst, cursor, nbr);

    int nb = (N_NODES + 63) / 64;

    for (int l = 0; l < L_LAYERS; ++l) {
        const float* xin;
        float* hbuf;
        if (l == 0)      { xin = x;  hbuf = B0; }
        else if (l == 1) { xin = B0; hbuf = B1; }
        else             { xin = B1; hbuf = B0; }

        // stats (128) + pooled (G*64) are adjacent: one memset
        hipMemsetAsync(stats, 0, (128 + (size_t)G_GRAPHS * 64) * sizeof(float), stream);

        gemm1_fused_kernel<<<nb, 256, 0, stream>>>(xin, rowptr, nbr,
            W1 + l * 64 * 64, b1 + l * 64, hbuf, stats);
        gemm2_pool_kernel<<<nb, 256, 0, stream>>>(hbuf, stats,
            gamma + l * 64, beta + l * 64, W2 + l * 64 * 64, b2 + l * 64, batch, pooled);
        out_kernel<<<(G_GRAPHS * OUT_F + 127) / 128, 128, 0, stream>>>(
            pooled, Wout + l * 64 * OUT_F, bout + l * OUT_F, out);
    }
}

// Round 7
// 542.020 us; speedup vs baseline: 1.9990x; 1.1570x over previous
//
#include <hip/hip_runtime.h>

typedef unsigned int uint;

#define N_NODES 100000
#define E_EDGES 1600000
#define L_LAYERS 3
#define G_GRAPHS 128
#define OUT_F 10
#define BN_EPS 1e-5f

#define NB4 (N_NODES / 4)                 // 25000 int4 chunks
#define SCAN_BLOCKS ((NB4 + 255) / 256)   // 98
#define BSHIFT 7                          // 128-node stripes for XCD ownership
#define CHUNK 2048
#define NCHUNK ((E_EDGES + CHUNK - 1) / CHUNK)   // 782

// bf16 pack (RTNE) / unpack-accumulate helpers
__device__ __forceinline__ uint bf_pack(float a, float b) {
    uint ua = __float_as_uint(a);
    ua = (ua + 0x7fffu + ((ua >> 16) & 1u)) >> 16;
    uint ub = __float_as_uint(b);
    ub = (ub + 0x7fffu + ((ub >> 16) & 1u)) >> 16;
    return ua | (ub << 16);
}
__device__ __forceinline__ unsigned short bf1(float a) {
    uint ua = __float_as_uint(a);
    return (unsigned short)((ua + 0x7fffu + ((ua >> 16) & 1u)) >> 16);
}
__device__ __forceinline__ void bf_acc(uint u, float& a0, float& a1) {
    a0 += __uint_as_float(u << 16);
    a1 += __uint_as_float(u & 0xffff0000u);
}

// -------------------- CSR build: degree histogram (int4) -----------------
__global__ __launch_bounds__(256) void deg_kernel(const int* __restrict__ dst,
                                                  int* __restrict__ deg) {
    int i = blockIdx.x * blockDim.x + threadIdx.x;   // E/4 threads
    if (i < E_EDGES / 4) {
        int4 d = reinterpret_cast<const int4*>(dst)[i];
        atomicAdd(&deg[d.x], 1);
        atomicAdd(&deg[d.y], 1);
        atomicAdd(&deg[d.z], 1);
        atomicAdd(&deg[d.w], 1);
    }
}

// -------------------- scan phase A: per-block sums -----------------------
__global__ __launch_bounds__(256) void scanA_kernel(const int* __restrict__ deg,
                                                    int* __restrict__ bsum) {
    __shared__ int red[256];
    int t = threadIdx.x;
    int i4 = blockIdx.x * 256 + t;
    int s = 0;
    if (i4 < NB4) {
        int4 v = reinterpret_cast<const int4*>(deg)[i4];
        s = v.x + v.y + v.z + v.w;
    }
    red[t] = s;
    __syncthreads();
    for (int off = 128; off > 0; off >>= 1) {
        if (t < off) red[t] += red[t + off];
        __syncthreads();
    }
    if (t == 0) bsum[blockIdx.x] = red[0];
}

// -------------------- scan phase B: scan the block sums ------------------
__global__ __launch_bounds__(128) void scanB_kernel(int* __restrict__ bsum,
                                                    int* __restrict__ rowptr) {
    __shared__ int p[128];
    int t = threadIdx.x;
    int v = (t < SCAN_BLOCKS) ? bsum[t] : 0;
    p[t] = v;
    __syncthreads();
    for (int off = 1; off < 128; off <<= 1) {
        int u = (t >= off) ? p[t - off] : 0;
        __syncthreads();
        p[t] += u;
        __syncthreads();
    }
    if (t < SCAN_BLOCKS) bsum[t] = p[t] - v;      // exclusive block offset
    if (t == 127) rowptr[N_NODES] = p[127];       // total
}

// ---------- scan phase C: write rowptr + cursor --------------------------
__global__ __launch_bounds__(256) void scanC_kernel(
    const int* __restrict__ deg, const int* __restrict__ bsum,
    int* __restrict__ rowptr, int* __restrict__ cursor) {
    __shared__ int ts[256];
    int t = threadIdx.x;
    int i4 = blockIdx.x * 256 + t;
    int4 v = make_int4(0, 0, 0, 0);
    if (i4 < NB4) v = reinterpret_cast<const int4*>(deg)[i4];
    int s = v.x + v.y + v.z + v.w;
    ts[t] = s;
    __syncthreads();
    for (int off = 1; off < 256; off <<= 1) {
        int u = (t >= off) ? ts[t - off] : 0;
        __syncthreads();
        ts[t] += u;
        __syncthreads();
    }
    if (i4 < NB4) {
        int base = bsum[blockIdx.x] + ts[t] - s;   // exclusive prefix
        int4 rp;
        rp.x = base;
        rp.y = rp.x + v.x;
        rp.z = rp.y + v.y;
        rp.w = rp.z + v.z;
        reinterpret_cast<int4*>(rowptr)[i4] = rp;
        reinterpret_cast<int4*>(cursor)[i4] = rp;
    }
}

// ------------- CSR fill: XCD-striped scatter ------------------------------
__global__ __launch_bounds__(256) void fill_kernel(
    const int* __restrict__ src, const int* __restrict__ dst,
    int* __restrict__ cursor, int* __restrict__ nbr) {
    int xcd = blockIdx.x & 7;
    int base = (blockIdx.x >> 3) * CHUNK;
    #pragma unroll
    for (int it = 0; it < CHUNK / 256; ++it) {
        int e = base + it * 256 + threadIdx.x;
        if (e < E_EDGES) {
            int d = dst[e];
            if (((d >> BSHIFT) & 7) == xcd) {
                int pos = atomicAdd(&cursor[d], 1);
                nbr[pos] = src[e];
            }
        }
    }
}

// -------------------- x f32 -> bf16 (layer 0 only) ------------------------
__global__ __launch_bounds__(256) void tobf_kernel(const float* __restrict__ x,
                                                   uint* __restrict__ xbf) {
    int i = blockIdx.x * 256 + threadIdx.x;   // N*8 threads, 8 floats each
    if (i < N_NODES * 8) {
        float4 a = reinterpret_cast<const float4*>(x)[i * 2];
        float4 b = reinterpret_cast<const float4*>(x)[i * 2 + 1];
        uint4 o;
        o.x = bf_pack(a.x, a.y);
        o.y = bf_pack(a.z, a.w);
        o.z = bf_pack(b.x, b.y);
        o.w = bf_pack(b.z, b.w);
        reinterpret_cast<uint4*>(xbf)[i] = o;
    }
}

// ------- fused gather(bf16) + GEMM1 + BN stats: h = (x+sum_nbr x)@W1+b1 ---
// 8 lanes per row (uint4 = 8 bf16), 8 neighbors in flight per lane.
__global__ __launch_bounds__(256) void gemm1_fused_kernel(
    const uint* __restrict__ xbf, const int* __restrict__ rowptr,
    const int* __restrict__ nbr, const float* __restrict__ W1,
    const float* __restrict__ b1, float* __restrict__ h,
    float* __restrict__ stats) {
    __shared__ float sA[64][64];
    __shared__ float sW[64][64];
    int tid = threadIdx.x;
    int row0 = blockIdx.x * 64;

    for (int i = tid; i < 1024; i += 256)
        reinterpret_cast<float4*>(&sW[0][0])[i] = reinterpret_cast<const float4*>(W1)[i];

    const uint4* xb4 = reinterpret_cast<const uint4*>(xbf);
    int c8 = tid & 7;        // uint4 slot within row (8 bf16 cols)
    int rl = tid >> 3;       // 32 rows per pass
    for (int rr = 0; rr < 2; ++rr) {
        int r = rl + 32 * rr;
        int gr = row0 + r;
        float a0 = 0.f, a1 = 0.f, a2 = 0.f, a3 = 0.f;
        float a4 = 0.f, a5 = 0.f, a6 = 0.f, a7 = 0.f;
        if (gr < N_NODES) {
            uint4 sv = xb4[gr * 8 + c8];
            bf_acc(sv.x, a0, a1); bf_acc(sv.y, a2, a3);
            bf_acc(sv.z, a4, a5); bf_acc(sv.w, a6, a7);
            int beg = rowptr[gr], end = rowptr[gr + 1];
            int j = beg;
            for (; j + 8 <= end; j += 8) {
                int s0 = nbr[j + 0], s1 = nbr[j + 1], s2 = nbr[j + 2], s3 = nbr[j + 3];
                int s4 = nbr[j + 4], s5 = nbr[j + 5], s6 = nbr[j + 6], s7 = nbr[j + 7];
                uint4 v0 = xb4[s0 * 8 + c8];
                uint4 v1 = xb4[s1 * 8 + c8];
                uint4 v2 = xb4[s2 * 8 + c8];
                uint4 v3 = xb4[s3 * 8 + c8];
                uint4 v4 = xb4[s4 * 8 + c8];
                uint4 v5 = xb4[s5 * 8 + c8];
                uint4 v6 = xb4[s6 * 8 + c8];
                uint4 v7 = xb4[s7 * 8 + c8];
                bf_acc(v0.x, a0, a1); bf_acc(v0.y, a2, a3); bf_acc(v0.z, a4, a5); bf_acc(v0.w, a6, a7);
                bf_acc(v1.x, a0, a1); bf_acc(v1.y, a2, a3); bf_acc(v1.z, a4, a5); bf_acc(v1.w, a6, a7);
                bf_acc(v2.x, a0, a1); bf_acc(v2.y, a2, a3); bf_acc(v2.z, a4, a5); bf_acc(v2.w, a6, a7);
                bf_acc(v3.x, a0, a1); bf_acc(v3.y, a2, a3); bf_acc(v3.z, a4, a5); bf_acc(v3.w, a6, a7);
                bf_acc(v4.x, a0, a1); bf_acc(v4.y, a2, a3); bf_acc(v4.z, a4, a5); bf_acc(v4.w, a6, a7);
                bf_acc(v5.x, a0, a1); bf_acc(v5.y, a2, a3); bf_acc(v5.z, a4, a5); bf_acc(v5.w, a6, a7);
                bf_acc(v6.x, a0, a1); bf_acc(v6.y, a2, a3); bf_acc(v6.z, a4, a5); bf_acc(v6.w, a6, a7);
                bf_acc(v7.x, a0, a1); bf_acc(v7.y, a2, a3); bf_acc(v7.z, a4, a5); bf_acc(v7.w, a6, a7);
            }
            for (; j < end; ++j) {
                uint4 v = xb4[nbr[j] * 8 + c8];
                bf_acc(v.x, a0, a1); bf_acc(v.y, a2, a3);
                bf_acc(v.z, a4, a5); bf_acc(v.w, a6, a7);
            }
        }
        *reinterpret_cast<float4*>(&sA[r][c8 * 8])     = make_float4(a0, a1, a2, a3);
        *reinterpret_cast<float4*>(&sA[r][c8 * 8 + 4]) = make_float4(a4, a5, a6, a7);
    }
    __syncthreads();

    int cc = tid & 63;
    int rbase = (tid >> 6) * 16;
    float bias = b1[cc];
    float lsum = 0.f, lsq = 0.f;
    float hout[16];
    for (int i = 0; i < 16; ++i) {
        int r = rbase + i;
        float acc = bias;
        #pragma unroll
        for (int k = 0; k < 64; ++k) acc += sA[r][k] * sW[k][cc];
        hout[i] = acc;
    }
    for (int i = 0; i < 16; ++i) {
        int gr = row0 + rbase + i;
        if (gr < N_NODES) {
            h[(size_t)gr * 64 + cc] = hout[i];
            lsum += hout[i];
            lsq += hout[i] * hout[i];
        }
    }
    // reuse sA as reduction scratch (all reads of sA are done)
    __syncthreads();
    float* red = &sA[0][0];
    red[tid] = lsum;
    red[256 + tid] = lsq;
    __syncthreads();
    if (tid < 64) {
        float s = red[tid] + red[tid + 64] + red[tid + 128] + red[tid + 192];
        float q = red[256 + tid] + red[256 + tid + 64] + red[256 + tid + 128] + red[256 + tid + 192];
        unsafeAtomicAdd(&stats[tid], s);
        unsafeAtomicAdd(&stats[64 + tid], q);
    }
}

// -- GEMM2 + pool: xn=relu(h*sc+sh)@W2+b2 ; pooled += xn (f32);
//    xn written as bf16 for the next layer's gather.
__global__ __launch_bounds__(256) void gemm2_pool_kernel(
    const float* __restrict__ h, const float* __restrict__ stats,
    const float* __restrict__ gamma, const float* __restrict__ beta,
    const float* __restrict__ W2, const float* __restrict__ b2,
    const int* __restrict__ batch, float* __restrict__ pooled,
    unsigned short* __restrict__ xout) {
    __shared__ float sA[64][64];
    __shared__ float sW[64][64];
    int tid = threadIdx.x;
    int row0 = blockIdx.x * 64;

    for (int i = tid; i < 1024; i += 256)
        reinterpret_cast<float4*>(&sW[0][0])[i] = reinterpret_cast<const float4*>(W2)[i];

    // per-thread BN scale/shift for its fixed 4 columns
    int c4 = tid & 15;
    float4 s1 = reinterpret_cast<const float4*>(stats)[c4];
    float4 s2 = reinterpret_cast<const float4*>(stats + 64)[c4];
    float4 g4 = reinterpret_cast<const float4*>(gamma)[c4];
    float4 bt4 = reinterpret_cast<const float4*>(beta)[c4];
    float4 sc, sh;
    {
        float mu, var;
        mu = s1.x * (1.0f / N_NODES); var = s2.x * (1.0f / N_NODES) - mu * mu;
        sc.x = g4.x * rsqrtf(var + BN_EPS); sh.x = bt4.x - mu * sc.x;
        mu = s1.y * (1.0f / N_NODES); var = s2.y * (1.0f / N_NODES) - mu * mu;
        sc.y = g4.y * rsqrtf(var + BN_EPS); sh.y = bt4.y - mu * sc.y;
        mu = s1.z * (1.0f / N_NODES); var = s2.z * (1.0f / N_NODES) - mu * mu;
        sc.z = g4.z * rsqrtf(var + BN_EPS); sh.z = bt4.z - mu * sc.z;
        mu = s1.w * (1.0f / N_NODES); var = s2.w * (1.0f / N_NODES) - mu * mu;
        sc.w = g4.w * rsqrtf(var + BN_EPS); sh.w = bt4.w - mu * sc.w;
    }

    for (int i = tid; i < 1024; i += 256) {
        int r = i >> 4;
        int gr = row0 + r;
        float4 a = make_float4(0.f, 0.f, 0.f, 0.f);
        if (gr < N_NODES) {
            float4 hv = reinterpret_cast<const float4*>(h)[gr * 16 + c4];
            a.x = fmaxf(fmaf(hv.x, sc.x, sh.x), 0.f);
            a.y = fmaxf(fmaf(hv.y, sc.y, sh.y), 0.f);
            a.z = fmaxf(fmaf(hv.z, sc.z, sh.z), 0.f);
            a.w = fmaxf(fmaf(hv.w, sc.w, sh.w), 0.f);
        }
        reinterpret_cast<float4*>(&sA[0][0])[i] = a;
    }
    __syncthreads();

    int c = tid & 63;
    int rbase = (tid >> 6) * 16;
    float bias = b2[c];
    float pacc = 0.f;
    int curb = -1;
    for (int i = 0; i < 16; ++i) {
        int r = rbase + i;
        int gr = row0 + r;
        float acc = bias;
        #pragma unroll
        for (int k = 0; k < 64; ++k) acc += sA[r][k] * sW[k][c];
        if (gr < N_NODES) {
            xout[(size_t)gr * 64 + c] = bf1(acc);
            int b = batch[gr];
            if (b != curb) {
                if (curb >= 0) unsafeAtomicAdd(&pooled[curb * 64 + c], pacc);
                curb = b;
                pacc = 0.f;
            }
            pacc += acc;
        }
    }
    if (curb >= 0) unsafeAtomicAdd(&pooled[curb * 64 + c], pacc);
}

// -------------------- output: score += pooled @ Wout + bout --------------
__global__ void out_kernel(const float* __restrict__ pooled,
                           const float* __restrict__ Wout,
                           const float* __restrict__ bout,
                           float* __restrict__ score) {
    int idx = blockIdx.x * blockDim.x + threadIdx.x;
    if (idx >= G_GRAPHS * OUT_F) return;
    int g = idx / OUT_F;
    int o = idx - g * OUT_F;
    float acc = bout[o];
    #pragma unroll
    for (int k = 0; k < 64; ++k) acc += pooled[g * 64 + k] * Wout[k * OUT_F + o];
    score[idx] += acc;
}

extern "C" void kernel_launch(void* const* d_in, const int* in_sizes, int n_in,
                              void* d_out, int out_size, void* d_ws, size_t ws_size,
                              hipStream_t stream) {
    const float* x     = (const float*)d_in[0];
    const int*   ei    = (const int*)d_in[1];
    const int*   batch = (const int*)d_in[2];
    const float* W1    = (const float*)d_in[3];
    const float* b1    = (const float*)d_in[4];
    const float* gamma = (const float*)d_in[5];
    const float* beta  = (const float*)d_in[6];
    const float* W2    = (const float*)d_in[7];
    const float* b2    = (const float*)d_in[8];
    const float* Wout  = (const float*)d_in[9];
    const float* bout  = (const float*)d_in[10];
    float* out = (float*)d_out;

    float* H      = (float*)d_ws;                            // N*64 f32
    uint*  XBF    = (uint*)(H + (size_t)N_NODES * 64);       // N*32 uints (bf16 x2)
    float* stats  = (float*)(XBF + (size_t)N_NODES * 32);    // 128
    float* pooled = stats + 128;                             // G*64 (adjacent)
    int*   deg    = (int*)(pooled + (size_t)G_GRAPHS * 64);  // N
    int*   rowptr = deg + N_NODES;                           // N+4
    int*   cursor = rowptr + N_NODES + 4;                    // N
    int*   bsum   = cursor + N_NODES;                        // SCAN_BLOCKS (pad 128)
    int*   nbr    = bsum + 128;                              // E

    const int* src = ei;
    const int* dst = ei + E_EDGES;

    hipMemsetAsync(d_out, 0, (size_t)G_GRAPHS * OUT_F * sizeof(float), stream);
    hipMemsetAsync(deg, 0, (size_t)N_NODES * sizeof(int), stream);

    deg_kernel<<<(E_EDGES / 4 + 255) / 256, 256, 0, stream>>>(dst, deg);
    scanA_kernel<<<SCAN_BLOCKS, 256, 0, stream>>>(deg, bsum);
    scanB_kernel<<<1, 128, 0, stream>>>(bsum, rowptr);
    scanC_kernel<<<SCAN_BLOCKS, 256, 0, stream>>>(deg, bsum, rowptr, cursor);
    fill_kernel<<<NCHUNK * 8, 256, 0, stream>>>(src, dst, cursor, nbr);
    tobf_kernel<<<(N_NODES * 8 + 255) / 256, 256, 0, stream>>>(x, XBF);

    int nb = (N_NODES + 63) / 64;

    for (int l = 0; l < L_LAYERS; ++l) {
        // stats (128) + pooled (G*64) are adjacent: one memset
        hipMemsetAsync(stats, 0, (128 + (size_t)G_GRAPHS * 64) * sizeof(float), stream);

        gemm1_fused_kernel<<<nb, 256, 0, stream>>>(XBF, rowptr, nbr,
            W1 + l * 64 * 64, b1 + l * 64, H, stats);
        gemm2_pool_kernel<<<nb, 256, 0, stream>>>(H, stats,
            gamma + l * 64, beta + l * 64, W2 + l * 64 * 64, b2 + l * 64, batch,
            pooled, (unsigned short*)XBF);
        out_kernel<<<(G_GRAPHS * OUT_F + 127) / 128, 128, 0, stream>>>(
            pooled, Wout + l * 64 * OUT_F, bout + l * OUT_F, out);
    }
}